// Round 1
// baseline (205.805 us; speedup 1.0000x reference)
//
#include <hip/hip_runtime.h>

#define N_IMG 32
#define C_IMG 3
#define H_IMG 224
#define W_IMG 224
#define NBINS 9
#define PI_F 3.14159265358979323846f

__device__ __forceinline__ int reflect_idx(int i, int n) {
    if (i < 0) return -i;
    if (i >= n) return 2 * n - 2 - i;
    return i;
}

// One thread per (n, i, j) output position of scale s. Loops c=0..2, o=0..8.
__global__ void __launch_bounds__(256) hog_loss_kernel(
    const float* __restrict__ imgs, const float* __restrict__ mask,
    const float* __restrict__ pred, const float* __restrict__ pw,
    const float* __restrict__ pb, int s, int Hs, int Ws,
    double* __restrict__ acc)
{
    __shared__ float spw[81];
    __shared__ float spb[9];
    if (threadIdx.x < 81) spw[threadIdx.x] = pw[threadIdx.x];
    if (threadIdx.x < 9)  spb[threadIdx.x] = pb[threadIdx.x];
    __syncthreads();

    int tid = blockIdx.x * blockDim.x + threadIdx.x;
    int total = N_IMG * Hs * Ws;
    float local = 0.0f;
    if (tid < total) {
        int j = tid % Ws;
        int t = tid / Ws;
        int i = t % Hs;
        int n = t / Hs;

        // block-mean of mask over the s x s pool window
        float msum = 0.0f;
        const float* mbase = mask + (size_t)n * H_IMG * W_IMG;
        for (int a = 0; a < s; ++a) {
            const float* mr = mbase + (size_t)(i * s + a) * W_IMG + j * s;
            for (int b = 0; b < s; ++b) msum += mr[b];
        }
        float M = msum / (float)(s * s);

        int y = i * s, x = j * s;
        int y0 = reflect_idx(y - 1, H_IMG), y2 = reflect_idx(y + 1, H_IMG);
        int x0 = reflect_idx(x - 1, W_IMG), x2 = reflect_idx(x + 1, W_IMG);

        float d2 = 0.0f;
        for (int c = 0; c < C_IMG; ++c) {
            const float* im = imgs + (size_t)(n * C_IMG + c) * H_IMG * W_IMG;
            float p00 = im[(size_t)y0 * W_IMG + x0];
            float p01 = im[(size_t)y0 * W_IMG + x];
            float p02 = im[(size_t)y0 * W_IMG + x2];
            float p10 = im[(size_t)y  * W_IMG + x0];
            float p12 = im[(size_t)y  * W_IMG + x2];
            float p20 = im[(size_t)y2 * W_IMG + x0];
            float p21 = im[(size_t)y2 * W_IMG + x];
            float p22 = im[(size_t)y2 * W_IMG + x2];

            // cross-correlation with Sobel kernels (lax.conv is cross-corr)
            float gx = (p00 - p02) + 2.0f * (p10 - p12) + (p20 - p22);
            float gy = (p00 - p20) + 2.0f * (p01 - p21) + (p02 - p22);

            float magv = sqrtf(gx * gx + gy * gy);
            float ph = atan2f(gx, gy);   // note: atan2(gx, gy) per reference
            int b = (int)floorf(ph / PI_F * 9.0f);
            b = ((b % NBINS) + NBINS) % NBINS;

            float h[9];
            float nrm2 = 0.0f;
            #pragma unroll
            for (int o = 0; o < 9; ++o) {
                h[o] = spw[o * 9 + b] * magv + spb[o];
                nrm2 += h[o] * h[o];
            }
            float inv = 1.0f / fmaxf(sqrtf(nrm2), 1e-12f);

            const float* pr = pred + ((size_t)(n * 27 + c * 9) * Hs + i) * Ws + j;
            size_t cstride = (size_t)Hs * Ws;
            #pragma unroll
            for (int o = 0; o < 9; ++o) {
                float dd = pr[(size_t)o * cstride] - h[o] * inv;
                d2 += dd * dd;
            }
        }
        local = M * d2 * (1.0f / 27.0f);
    }

    // block reduction: wave shuffle then LDS across 4 waves, one atomic/block
    #pragma unroll
    for (int off = 32; off > 0; off >>= 1)
        local += __shfl_down(local, off, 64);
    __shared__ float wsum[4];
    int lane = threadIdx.x & 63, wid = threadIdx.x >> 6;
    if (lane == 0) wsum[wid] = local;
    __syncthreads();
    if (threadIdx.x == 0) {
        float bs = wsum[0] + wsum[1] + wsum[2] + wsum[3];
        atomicAdd(acc, (double)bs);
    }
}

__global__ void __launch_bounds__(256) mask_sum_kernel(
    const float* __restrict__ mask, int total, double* __restrict__ acc)
{
    float local = 0.0f;
    for (int idx = blockIdx.x * blockDim.x + threadIdx.x; idx < total;
         idx += gridDim.x * blockDim.x)
        local += mask[idx];
    #pragma unroll
    for (int off = 32; off > 0; off >>= 1)
        local += __shfl_down(local, off, 64);
    __shared__ float wsum[4];
    int lane = threadIdx.x & 63, wid = threadIdx.x >> 6;
    if (lane == 0) wsum[wid] = local;
    __syncthreads();
    if (threadIdx.x == 0) {
        float bs = wsum[0] + wsum[1] + wsum[2] + wsum[3];
        atomicAdd(acc, (double)bs);
    }
}

__global__ void finalize_kernel(const double* __restrict__ acc, float* __restrict__ out)
{
    // acc[0..4]: per-scale weighted sums; acc[5]: sum(mask)
    const int sc[5] = {16, 8, 4, 2, 1};
    double S = acc[5];
    double loss = 0.0;
    for (int k = 0; k < 5; ++k)
        loss += acc[k] * (double)(sc[k] * sc[k]) / S;
    out[0] = (float)loss;
}

extern "C" void kernel_launch(void* const* d_in, const int* in_sizes, int n_in,
                              void* d_out, int out_size, void* d_ws, size_t ws_size,
                              hipStream_t stream) {
    (void)in_sizes; (void)n_in; (void)out_size; (void)ws_size;
    const float* imgs = (const float*)d_in[0];
    const float* mask = (const float*)d_in[1];
    double* acc = (double*)d_ws;

    hipMemsetAsync(d_ws, 0, 6 * sizeof(double), stream);

    mask_sum_kernel<<<1024, 256, 0, stream>>>(mask, N_IMG * H_IMG * W_IMG, acc + 5);

    const int scales[5] = {16, 8, 4, 2, 1};
    for (int k = 0; k < 5; ++k) {
        int s = scales[k];
        int Hs = H_IMG / s, Ws = W_IMG / s;
        // setup_inputs dict order: imgs, mask, then (pred, pw, pb) per scale
        const float* pred = (const float*)d_in[2 + 3 * k];
        const float* pw   = (const float*)d_in[3 + 3 * k];
        const float* pb   = (const float*)d_in[4 + 3 * k];
        int total = N_IMG * Hs * Ws;
        int blocks = (total + 255) / 256;
        hog_loss_kernel<<<blocks, 256, 0, stream>>>(imgs, mask, pred, pw, pb,
                                                    s, Hs, Ws, acc + k);
    }
    finalize_kernel<<<1, 1, 0, stream>>>(acc, (float*)d_out);
}

// Round 2
// 96.975 us; speedup vs baseline: 2.1223x; 2.1223x over previous
//
#include <hip/hip_runtime.h>

#define N_IMG 32
#define H_IMG 224
#define W_IMG 224
#define PI_F 3.14159265358979323846f

// block ranges in the fused grid (see kernel_launch):
// S=1 : [0, 1568)      32*224*56 vec4-threads
// S=2 : [1568, 1960)   32*112*28
// S=4 : [1960, 2058)   32*56*14
// S=8 : [2058, 2083)   32*28*7  (last block partial)
// S=16: [2083, 2108)   32*14*14 scalar (last block partial)
#define NBLK_TOTAL 2108
#define B1_END 1568
#define B2_END 1960
#define B4_END 2058
#define B8_END 2083

__device__ __forceinline__ int reflect_idx(int i, int n) {
    if (i < 0) return -i;
    if (i >= n) return 2 * n - 2 - i;
    return i;
}

// HOG feature (normalized, 9 channels) for one (point, img-channel)
__device__ __forceinline__ void compute_hog(const float* __restrict__ im,
        int y, int x, const float* spw, const float* spb, float h[9])
{
    int y0 = reflect_idx(y - 1, H_IMG), y2 = reflect_idx(y + 1, H_IMG);
    int x0 = reflect_idx(x - 1, W_IMG), x2 = reflect_idx(x + 1, W_IMG);
    float p00 = im[(size_t)y0 * W_IMG + x0];
    float p01 = im[(size_t)y0 * W_IMG + x];
    float p02 = im[(size_t)y0 * W_IMG + x2];
    float p10 = im[(size_t)y  * W_IMG + x0];
    float p12 = im[(size_t)y  * W_IMG + x2];
    float p20 = im[(size_t)y2 * W_IMG + x0];
    float p21 = im[(size_t)y2 * W_IMG + x];
    float p22 = im[(size_t)y2 * W_IMG + x2];
    float gx = (p00 - p02) + 2.0f * (p10 - p12) + (p20 - p22);
    float gy = (p00 - p20) + 2.0f * (p01 - p21) + (p02 - p22);
    float magv = sqrtf(gx * gx + gy * gy);
    float ph = atan2f(gx, gy);
    int b = (int)floorf(ph * (9.0f / PI_F));
    b = ((b % 9) + 9) % 9;
    float n2 = 0.0f;
    #pragma unroll
    for (int o = 0; o < 9; ++o) { h[o] = spw[o * 9 + b] * magv + spb[o]; n2 += h[o] * h[o]; }
    float inv = 1.0f / fmaxf(sqrtf(n2), 1e-12f);
    #pragma unroll
    for (int o = 0; o < 9; ++o) h[o] *= inv;
}

// S==1 vec4 specialization: 4 adjacent outputs share Sobel window columns.
__device__ __forceinline__ void compute_hog4_s1(const float* __restrict__ im,
        int y, int j0, const float* spw, const float* spb, float hv[4][9])
{
    int y0 = reflect_idx(y - 1, H_IMG), y2 = reflect_idx(y + 1, H_IMG);
    int xc[6];
    #pragma unroll
    for (int u = 0; u < 6; ++u) xc[u] = reflect_idx(j0 - 1 + u, W_IMG);
    float r0[6], r1[6], r2[6];
    const float* q0 = im + (size_t)y0 * W_IMG;
    const float* q1 = im + (size_t)y  * W_IMG;
    const float* q2 = im + (size_t)y2 * W_IMG;
    #pragma unroll
    for (int u = 0; u < 6; ++u) { r0[u] = q0[xc[u]]; r1[u] = q1[xc[u]]; r2[u] = q2[xc[u]]; }
    #pragma unroll
    for (int v = 0; v < 4; ++v) {
        float gx = (r0[v] - r0[v + 2]) + 2.0f * (r1[v] - r1[v + 2]) + (r2[v] - r2[v + 2]);
        float gy = (r0[v] - r2[v]) + 2.0f * (r0[v + 1] - r2[v + 1]) + (r0[v + 2] - r2[v + 2]);
        float magv = sqrtf(gx * gx + gy * gy);
        float ph = atan2f(gx, gy);
        int b = (int)floorf(ph * (9.0f / PI_F));
        b = ((b % 9) + 9) % 9;
        float n2 = 0.0f;
        #pragma unroll
        for (int o = 0; o < 9; ++o) { hv[v][o] = spw[o * 9 + b] * magv + spb[o]; n2 += hv[v][o] * hv[v][o]; }
        float inv = 1.0f / fmaxf(sqrtf(n2), 1e-12f);
        #pragma unroll
        for (int o = 0; o < 9; ++o) hv[v][o] *= inv;
    }
}

template <int S, int VEC>
__device__ __forceinline__ void scale_body(int rel_bid,
    const float* __restrict__ imgs, const float* __restrict__ mask,
    const float* __restrict__ pred, const float* __restrict__ pw,
    const float* __restrict__ pb, float& local, float& mlocal)
{
    __shared__ float spw[81];
    __shared__ float spb[9];
    if (threadIdx.x < 81) spw[threadIdx.x] = pw[threadIdx.x];
    if (threadIdx.x < 9)  spb[threadIdx.x] = pb[threadIdx.x];
    __syncthreads();

    constexpr int Hs = H_IMG / S, Ws = W_IMG / S;
    constexpr int WsV = Ws / VEC;
    int vt = rel_bid * 256 + (int)threadIdx.x;
    if (vt >= N_IMG * Hs * WsV) return;  // local/mlocal stay 0
    int jv = vt % WsV;
    int t  = vt / WsV;
    int i  = t % Hs;
    int n  = t / Hs;
    int j0 = jv * VEC;

    // ---- mask pooling: per row, S*VEC contiguous floats as float4s ----
    float msum[VEC];
    #pragma unroll
    for (int v = 0; v < VEC; ++v) msum[v] = 0.0f;
    const float* mbase = mask + (size_t)n * H_IMG * W_IMG;
    #pragma unroll
    for (int a = 0; a < S; ++a) {
        const float* mr = mbase + (size_t)(i * S + a) * W_IMG + j0 * S;
        #pragma unroll
        for (int q = 0; q < (S * VEC) / 4; ++q) {
            float4 mv = *(const float4*)(mr + q * 4);
            float me[4] = {mv.x, mv.y, mv.z, mv.w};
            #pragma unroll
            for (int u = 0; u < 4; ++u) msum[(q * 4 + u) / S] += me[u];
        }
    }

    // ---- HOG + pred diff ----
    float d2[VEC];
    #pragma unroll
    for (int v = 0; v < VEC; ++v) d2[v] = 0.0f;
    constexpr size_t cstride = (size_t)Hs * Ws;

    for (int c = 0; c < 3; ++c) {
        const float* im = imgs + (size_t)(n * 3 + c) * H_IMG * W_IMG;
        float hv[VEC][9];
        if constexpr (S == 1 && VEC == 4) {
            compute_hog4_s1(im, i, j0, spw, spb, hv);
        } else {
            #pragma unroll
            for (int v = 0; v < VEC; ++v)
                compute_hog(im, i * S, (j0 + v) * S, spw, spb, hv[v]);
        }
        const float* pr = pred + ((size_t)(n * 27 + c * 9) * Hs + i) * Ws + j0;
        #pragma unroll
        for (int o = 0; o < 9; ++o) {
            if constexpr (VEC == 4) {
                float4 p = *(const float4*)(pr + o * cstride);
                float pe[4] = {p.x, p.y, p.z, p.w};
                #pragma unroll
                for (int u = 0; u < 4; ++u) { float dd = pe[u] - hv[u][o]; d2[u] += dd * dd; }
            } else {
                float dd = pr[o * cstride] - hv[0][o];
                d2[0] += dd * dd;
            }
        }
    }

    float acc = 0.0f, macc = 0.0f;
    #pragma unroll
    for (int v = 0; v < VEC; ++v) {
        float M = msum[v] * (1.0f / (float)(S * S));
        acc += M * d2[v];
        macc += M;
    }
    local = acc * (1.0f / 27.0f);
    if (S == 1) mlocal = macc;   // sum of M at s=1 == sum(mask)
}

__global__ void __launch_bounds__(256) fused_kernel(
    const float* __restrict__ imgs, const float* __restrict__ mask,
    const float* __restrict__ pred0, const float* __restrict__ pred1,
    const float* __restrict__ pred2, const float* __restrict__ pred3,
    const float* __restrict__ pred4,
    const float* __restrict__ pw0, const float* __restrict__ pw1,
    const float* __restrict__ pw2, const float* __restrict__ pw3,
    const float* __restrict__ pw4,
    const float* __restrict__ pb0, const float* __restrict__ pb1,
    const float* __restrict__ pb2, const float* __restrict__ pb3,
    const float* __restrict__ pb4,
    double* __restrict__ pl, double* __restrict__ pm)
{
    int bid = blockIdx.x;
    float local = 0.0f, mlocal = 0.0f;
    // input order: k=0 -> s=16 ... k=4 -> s=1
    if (bid < B1_END)       scale_body<1, 4>(bid,           imgs, mask, pred4, pw4, pb4, local, mlocal);
    else if (bid < B2_END)  scale_body<2, 4>(bid - B1_END,  imgs, mask, pred3, pw3, pb3, local, mlocal);
    else if (bid < B4_END)  scale_body<4, 4>(bid - B2_END,  imgs, mask, pred2, pw2, pb2, local, mlocal);
    else if (bid < B8_END)  scale_body<8, 4>(bid - B4_END,  imgs, mask, pred1, pw1, pb1, local, mlocal);
    else                    scale_body<16, 1>(bid - B8_END, imgs, mask, pred0, pw0, pb0, local, mlocal);

    #pragma unroll
    for (int off = 32; off > 0; off >>= 1) {
        local  += __shfl_down(local,  off, 64);
        mlocal += __shfl_down(mlocal, off, 64);
    }
    __shared__ float s1[4], s2[4];
    int lane = threadIdx.x & 63, wid = threadIdx.x >> 6;
    if (lane == 0) { s1[wid] = local; s2[wid] = mlocal; }
    __syncthreads();
    if (threadIdx.x == 0) {
        pl[bid] = (double)(s1[0] + s1[1] + s1[2] + s1[3]);
        pm[bid] = (double)(s2[0] + s2[1] + s2[2] + s2[3]);
    }
}

__global__ void __launch_bounds__(256) finalize_kernel(
    const double* __restrict__ pl, const double* __restrict__ pm,
    float* __restrict__ out)
{
    double l = 0.0, m = 0.0;
    for (int idx = threadIdx.x; idx < NBLK_TOTAL; idx += 256) {
        double w = (idx < B1_END) ? 1.0 : (idx < B2_END) ? 4.0
                 : (idx < B4_END) ? 16.0 : (idx < B8_END) ? 64.0 : 256.0;
        l += w * pl[idx];
    }
    for (int idx = threadIdx.x; idx < B1_END; idx += 256) m += pm[idx];
    #pragma unroll
    for (int off = 32; off > 0; off >>= 1) {
        l += __shfl_down(l, off, 64);
        m += __shfl_down(m, off, 64);
    }
    __shared__ double sl[4], sm[4];
    int lane = threadIdx.x & 63, wid = threadIdx.x >> 6;
    if (lane == 0) { sl[wid] = l; sm[wid] = m; }
    __syncthreads();
    if (threadIdx.x == 0)
        out[0] = (float)((sl[0] + sl[1] + sl[2] + sl[3]) / (sm[0] + sm[1] + sm[2] + sm[3]));
}

extern "C" void kernel_launch(void* const* d_in, const int* in_sizes, int n_in,
                              void* d_out, int out_size, void* d_ws, size_t ws_size,
                              hipStream_t stream) {
    (void)in_sizes; (void)n_in; (void)out_size; (void)ws_size;
    const float* imgs = (const float*)d_in[0];
    const float* mask = (const float*)d_in[1];
    const float* pred[5];
    const float* pw[5];
    const float* pb[5];
    for (int k = 0; k < 5; ++k) {
        pred[k] = (const float*)d_in[2 + 3 * k];
        pw[k]   = (const float*)d_in[3 + 3 * k];
        pb[k]   = (const float*)d_in[4 + 3 * k];
    }
    double* pl = (double*)d_ws;
    double* pm = pl + NBLK_TOTAL;

    fused_kernel<<<NBLK_TOTAL, 256, 0, stream>>>(
        imgs, mask,
        pred[0], pred[1], pred[2], pred[3], pred[4],
        pw[0], pw[1], pw[2], pw[3], pw[4],
        pb[0], pb[1], pb[2], pb[3], pb[4],
        pl, pm);
    finalize_kernel<<<1, 256, 0, stream>>>(pl, pm, (float*)d_out);
}